// Round 14
// baseline (367.362 us; speedup 1.0000x reference)
//
#include <hip/hip_runtime.h>
#include <math.h>

#define N_NODES 25000
#define N_EDGES 400000
#define FEAT 128
#define HID 64
#define HEADS 4
#define HH 256   // HEADS*HID
#define NUM_GRAPHS 64
#define BUCKET 96   // max in-degree slot count (mean 16, sigma 4 -> P(>96)~1e-80)

typedef unsigned short ushort_t;
typedef unsigned int uint_t;

__device__ __forceinline__ float lrelu(float x){ return x > 0.f ? x : 0.2f*x; }

// fp32 -> bf16 with round-to-nearest-even
__device__ __forceinline__ ushort_t f2bf(float f){
  uint_t u = __float_as_uint(f);
  return (ushort_t)((u + 0x7fffu + ((u >> 16) & 1u)) >> 16);
}
#define BF_LO(u) __uint_as_float((u) << 16)
#define BF_HI(u) __uint_as_float((u) & 0xffff0000u)

// ============ conv1: dual GEMM (rel+root), K=128 split 2x64, M=64 ============
__global__ __launch_bounds__(256) void conv1_gemm(
    const float* __restrict__ X, const float* __restrict__ Wrel,
    const float* __restrict__ Wroot, const float* __restrict__ bias,
    ushort_t* __restrict__ out_rel_b, float* __restrict__ out_root)
{
  const int w    = __builtin_amdgcn_readfirstlane(threadIdx.x >> 6);
  const int lane = threadIdx.x & 63;
  const int m = w >> 1, q = w & 1;
  const float* Wm = (m ? Wroot : Wrel) + (size_t)q*64*HID;
  float wreg[64];
  #pragma unroll
  for (int k = 0; k < 64; k++) wreg[k] = Wm[k*HID + lane];
  __shared__ float part[2][2][8][64];          // 8 KB
  const int base = blockIdx.x*8;               // exact grid: 3125 blocks
  const float* __restrict__ xr = X + (size_t)base*FEAT + q*64;
  float acc[8] = {0,0,0,0,0,0,0,0};
  #pragma unroll
  for (int k = 0; k < 64; k++){
    const float wv = wreg[k];
    #pragma unroll
    for (int i = 0; i < 8; i++) acc[i] += xr[(size_t)i*FEAT + k]*wv;
  }
  #pragma unroll
  for (int i = 0; i < 8; i++) part[m][q][i][lane] = acc[i];
  __syncthreads();
  #pragma unroll
  for (int t = threadIdx.x; t < 1024; t += 256){
    int mm = t >> 9, ii = (t >> 6) & 7, cc = t & 63;
    float v = part[mm][0][ii][cc] + part[mm][1][ii][cc];
    if (mm) out_root[(size_t)(base+ii)*HID + cc] = v + bias[cc];
    else    out_rel_b[(size_t)(base+ii)*HID + cc] = f2bf(v);
  }
}

// ============ conv5: dual GEMM, K=256 split 4x64, M=64 =======================
__global__ __launch_bounds__(512) void conv5_gemm(
    const float* __restrict__ X, const float* __restrict__ Wrel,
    const float* __restrict__ Wroot, const float* __restrict__ bias,
    ushort_t* __restrict__ out_rel_b, float* __restrict__ out_root)
{
  const int w    = __builtin_amdgcn_readfirstlane(threadIdx.x >> 6);
  const int lane = threadIdx.x & 63;
  const int m = w >> 2, q = w & 3;
  const float* Wm = (m ? Wroot : Wrel) + (size_t)q*64*HID;
  float wreg[64];
  #pragma unroll
  for (int k = 0; k < 64; k++) wreg[k] = Wm[k*HID + lane];
  __shared__ float part[2][4][8][64];          // 16 KB
  const int base = blockIdx.x*8;               // exact grid: 3125 blocks
  const float* __restrict__ xr = X + (size_t)base*HH + q*64;
  float acc[8] = {0,0,0,0,0,0,0,0};
  #pragma unroll
  for (int k = 0; k < 64; k++){
    const float wv = wreg[k];
    #pragma unroll
    for (int i = 0; i < 8; i++) acc[i] += xr[(size_t)i*HH + k]*wv;
  }
  #pragma unroll
  for (int i = 0; i < 8; i++) part[m][q][i][lane] = acc[i];
  __syncthreads();
  #pragma unroll
  for (int t = threadIdx.x; t < 1024; t += 512){
    int mm = t >> 9, ii = (t >> 6) & 7, cc = t & 63;
    float v = part[mm][0][ii][cc] + part[mm][1][ii][cc]
            + part[mm][2][ii][cc] + part[mm][3][ii][cc];
    if (mm) out_root[(size_t)(base+ii)*HID + cc] = v + bias[cc];
    else    out_rel_b[(size_t)(base+ii)*HID + cc] = f2bf(v);
  }
}

// ============ GAT transform v3: weights in LDS, acc[8] in regs ===============
// 782 blocks x 32 nodes. Thread owns col hc; weight read = 1 ds_read_b32/k
// (2-way bank aliasing = free); activations = wave-uniform s_loads.
__global__ __launch_bounds__(256) void k3_gat_transform(
    const float* __restrict__ h1, const float* __restrict__ Wg,
    const float* __restrict__ att_src, const float* __restrict__ att_dst,
    ushort_t* __restrict__ xlb, float* __restrict__ a_s, float* __restrict__ a_d)
{
  __shared__ float wg[HID*HH];                 // exactly 64 KB
  {
    float4* wg4 = (float4*)wg;
    const float4* Wg4 = (const float4*)Wg;
    #pragma unroll
    for (int i = 0; i < 16; i++)
      wg4[threadIdx.x + i*256] = Wg4[threadIdx.x + i*256];
  }
  __syncthreads();
  const int hc = threadIdx.x, lane = hc & 63;
  const int h  = __builtin_amdgcn_readfirstlane(hc >> 6);
  const float asv = att_src[h*HID + lane];
  const float adv = att_dst[h*HID + lane];
  #pragma unroll
  for (int gq = 0; gq < 4; gq++){
    const int nb = blockIdx.x*32 + gq*8;
    if (nb >= N_NODES) break;                  // tail block (8 nodes)
    const float* __restrict__ xr = h1 + (size_t)nb*HID;
    float acc[8] = {0,0,0,0,0,0,0,0};
    #pragma unroll
    for (int k = 0; k < 64; k++){
      const float wv = wg[k*HH + hc];
      #pragma unroll
      for (int i = 0; i < 8; i++) acc[i] += xr[i*HID + k]*wv;
    }
    #pragma unroll
    for (int i = 0; i < 8; i++){
      xlb[(size_t)(nb+i)*HH + hc] = f2bf(acc[i]);
      float s1 = acc[i]*asv, s2 = acc[i]*adv;
      #pragma unroll
      for (int off = 32; off; off >>= 1){
        s1 += __shfl_xor(s1, off, 64);
        s2 += __shfl_xor(s2, off, 64);
      }
      if (lane == 0){
        a_s[(nb+i)*HEADS + h] = s1;
        a_d[(nb+i)*HEADS + h] = s2;
      }
    }
  }
}

// -------- bucketed CSR build: no histogram, no scan --------------------------
__global__ __launch_bounds__(256) void k_fill(const int* __restrict__ src,
                                              const int* __restrict__ dst,
                                              int* __restrict__ cnt,
                                              int* __restrict__ slot)
{
  int e = blockIdx.x*256 + threadIdx.x;
  if (e >= N_EDGES) return;
  int d = dst[e];
  int pos = atomicAdd(&cnt[d], 1);
  if (pos < BUCKET) slot[(size_t)d*BUCKET + pos] = src[e];
}

// -------- gather agg v2: wave=node, lane=column; 1 coalesced row load/edge ---
__global__ __launch_bounds__(256) void k_aggb(
    const int* __restrict__ cnt, const int* __restrict__ slot,
    const ushort_t* __restrict__ featb, const float* __restrict__ root,
    float* __restrict__ outp)
{
  const int node = blockIdx.x*4 + (threadIdx.x >> 6);   // grid exact: 6250*4
  const int lane = threadIdx.x & 63;
  const int* __restrict__ sl = slot + (size_t)node*BUCKET;
  const int deg = min(cnt[node], BUCKET);
  float acc = root[(size_t)node*HID + lane];
  int e = 0;
  for (; e + 4 <= deg; e += 4){
    int sA = sl[e],   sB = sl[e+1];
    int sC = sl[e+2], sD = sl[e+3];
    float xA = BF_LO((uint_t)featb[(size_t)sA*HID + lane]);
    float xB = BF_LO((uint_t)featb[(size_t)sB*HID + lane]);
    float xC = BF_LO((uint_t)featb[(size_t)sC*HID + lane]);
    float xD = BF_LO((uint_t)featb[(size_t)sD*HID + lane]);
    acc += xA; acc += xB; acc += xC; acc += xD;
  }
  for (; e < deg; e++){
    int s = sl[e];
    acc += BF_LO((uint_t)featb[(size_t)s*HID + lane]);
  }
  outp[(size_t)node*HID + lane] = fmaxf(acc, 0.f);
}

// ---- GAT softmax+aggregate v4: wave = node (ALL 4 heads) --------------------
__global__ __launch_bounds__(256) void k_gat_node(
    const int* __restrict__ cnt, const int* __restrict__ slot,
    const uint2* __restrict__ xl2,      // bf16 node-major: idx = node*64 + lane
    const float* __restrict__ a_s, const float* __restrict__ a_d,
    const float* __restrict__ bg, float* __restrict__ h2)
{
  const int node = blockIdx.x*4 + (threadIdx.x >> 6);   // grid exact: 6250*4
  const int lane = threadIdx.x & 63;
  const int h  = lane >> 4;
  const int el = lane & 15;
  const int* __restrict__ sl = slot + (size_t)node*BUCKET;
  const int deg = min(cnt[node], BUCKET);
  const float adh = a_d[node*HEADS + h];
  float acc0=0, acc1=0, acc2=0, acc3=0;
  float dsum = 0.f;
  for (int base = 0; base < deg; base += 16){
    // phase 1: this lane's (edge, head)
    float pme = 0.f; int sme = node;
    const int e = base + el;
    if (e < deg){
      sme = sl[e];
      pme = __expf(lrelu(a_s[sme*HEADS + h] + adh));
    }
    dsum += pme;
    // phase 2: iterate chunk edges; broadcast (p, src) from lane h*16+e4
    const int nsub = min(16, deg - base);
    int e4 = 0;
    for (; e4 + 2 <= nsub; e4 += 2){
      const int b0 = (lane & 48) + e4;
      const float pA = __shfl(pme, b0, 64);
      const int   sA = __shfl(sme, b0, 64);
      const float pB = __shfl(pme, b0 + 1, 64);
      const int   sB = __shfl(sme, b0 + 1, 64);
      uint2 rA = xl2[(size_t)sA*64 + lane];
      uint2 rB = xl2[(size_t)sB*64 + lane];
      acc0 += pA*BF_LO(rA.x); acc1 += pA*BF_HI(rA.x);
      acc2 += pA*BF_LO(rA.y); acc3 += pA*BF_HI(rA.y);
      acc0 += pB*BF_LO(rB.x); acc1 += pB*BF_HI(rB.x);
      acc2 += pB*BF_LO(rB.y); acc3 += pB*BF_HI(rB.y);
    }
    if (e4 < nsub){
      const int b0 = (lane & 48) + e4;
      const float pA = __shfl(pme, b0, 64);
      const int   sA = __shfl(sme, b0, 64);
      uint2 rA = xl2[(size_t)sA*64 + lane];
      acc0 += pA*BF_LO(rA.x); acc1 += pA*BF_HI(rA.x);
      acc2 += pA*BF_LO(rA.y); acc3 += pA*BF_HI(rA.y);
    }
  }
  // denom reduce within the 16-lane head group
  #pragma unroll
  for (int off = 1; off < 16; off <<= 1) dsum += __shfl_xor(dsum, off, 64);
  // self loop + epilogue
  const float pself = __expf(lrelu(a_s[node*HEADS + h] + adh));
  const float inv = 1.f / (dsum + pself);
  uint2 r = xl2[(size_t)node*64 + lane];
  acc0 += pself*BF_LO(r.x); acc1 += pself*BF_HI(r.x);
  acc2 += pself*BF_LO(r.y); acc3 += pself*BF_HI(r.y);
  const int col0 = lane*4;          // = h*64 + el*4
  float4 o;
  o.x = fmaxf(acc0*inv + bg[col0+0], 0.f);
  o.y = fmaxf(acc1*inv + bg[col0+1], 0.f);
  o.z = fmaxf(acc2*inv + bg[col0+2], 0.f);
  o.w = fmaxf(acc3*inv + bg[col0+3], 0.f);
  ((float4*)(h2 + (size_t)node*HH))[lane] = o;
}

// ---------------- pool: run-length segment reduce over sorted batch ----------
__global__ __launch_bounds__(256) void k_pool(
    const float* __restrict__ h3, const int* __restrict__ batch,
    float* __restrict__ g)
{
  const int w = blockIdx.x*4 + (threadIdx.x >> 6);
  const int j = threadIdx.x & 63;
  int n0 = w*64;
  if (n0 >= N_NODES) return;
  int n1 = min(n0+64, N_NODES);
  float acc = 0.f;
  int cur = batch[n0];
  for (int n = n0; n < n1; n++){
    int b = batch[n];
    if (b != cur){ atomicAdd(&g[cur*HID + j], acc); acc = 0.f; cur = b; }
    acc += h3[n*HID + j];
  }
  atomicAdd(&g[cur*HID + j], acc);
}

__global__ __launch_bounds__(256) void k_head(
    const float* __restrict__ g, const float* __restrict__ W1,
    const float* __restrict__ b1, const float* __restrict__ W2,
    const float* __restrict__ b2, float* __restrict__ out)
{
  __shared__ float gs[NUM_GRAPHS*HID];
  __shared__ float hh[NUM_GRAPHS*HID];
  for (int i = threadIdx.x; i < NUM_GRAPHS*HID; i += 256) gs[i] = g[i];
  __syncthreads();
  for (int t = threadIdx.x; t < NUM_GRAPHS*HID; t += 256){
    int b = t >> 6, j = t & 63;
    float acc = b1[j];
    for (int k = 0; k < HID; k++) acc += gs[b*HID+k]*W1[k*HID+j];
    hh[t] = fmaxf(acc, 0.f);
  }
  __syncthreads();
  for (int t = threadIdx.x; t < NUM_GRAPHS*2; t += 256){
    int b = t >> 1, c = t & 1;
    float acc = b2[c];
    for (int k = 0; k < HID; k++) acc += hh[b*HID+k]*W2[k*2+c];
    out[t] = 1.f / (1.f + __expf(-acc));
  }
}

extern "C" void kernel_launch(void* const* d_in, const int* in_sizes, int n_in,
                              void* d_out, int out_size, void* d_ws, size_t ws_size,
                              hipStream_t stream)
{
  const float* x       = (const float*)d_in[0];
  const int*   ei      = (const int*)d_in[1];
  const int*   batch   = (const int*)d_in[2];
  const float* W1_rel  = (const float*)d_in[3];
  const float* b1      = (const float*)d_in[4];
  const float* W1_root = (const float*)d_in[5];
  const float* Wg      = (const float*)d_in[6];
  const float* att_src = (const float*)d_in[7];
  const float* att_dst = (const float*)d_in[8];
  const float* bg      = (const float*)d_in[9];
  const float* W5_rel  = (const float*)d_in[10];
  const float* b5      = (const float*)d_in[11];
  const float* W5_root = (const float*)d_in[12];
  const float* W_fc1   = (const float*)d_in[13];
  const float* b_fc1   = (const float*)d_in[14];
  const float* W_fc2   = (const float*)d_in[15];
  const float* b_fc2   = (const float*)d_in[16];
  const int* src = ei;
  const int* dst = ei + N_EDGES;

  // ---- workspace layout, FLOAT (4-byte) units, all 16B-aligned -------------
  float* ws    = (float*)d_ws;
  ushort_t* xr_b = (ushort_t*)ws;            // bf16 N*64      [0, 800000)
  float* hB    = ws +   800000;              // f32 N*64       [800000, 2400000)
  ushort_t* xlb = (ushort_t*)(ws + 2400000); // bf16 N*256 nm  [2400000, 5600000)
  float* a_s   = ws +  5600000;              // f32 N*4
  float* a_d   = ws +  5700000;              // f32 N*4
  float* h2    = ws +  5800000;              // f32 N*256      [5800000, 12200000)
  float* g     = ws + 12200000;              // 4096
  int*   ib    = (int*)(ws + 12204096);      // cnt adjacent to g -> one memset
  int* cnt      = ib;                        // 25000
  int* slot     = ib + 25024;                // 25000*96 = 2.4M ints
  float* out   = (float*)d_out;

  // bucketed CSR build (+ zero g and cnt in the same memset)
  hipMemsetAsync(g, 0, (4096 + N_NODES)*sizeof(float), stream);
  k_fill<<<(N_EDGES+255)/256,256,0,stream>>>(src, dst, cnt, slot);

  // conv1  (3125 blocks x 8 nodes)
  conv1_gemm<<<N_NODES/8,256,0,stream>>>(x, W1_rel, W1_root, b1, xr_b, hB);
  k_aggb<<<N_NODES/4,256,0,stream>>>(cnt, slot, xr_b, hB, hB);

  // GAT   (782 blocks x 32 nodes)
  k3_gat_transform<<<(N_NODES+31)/32,256,0,stream>>>(hB, Wg, att_src, att_dst, xlb, a_s, a_d);
  k_gat_node<<<N_NODES/4,256,0,stream>>>(cnt, slot,
      (const uint2*)xlb, a_s, a_d, bg, h2);

  // conv5  (3125 blocks x 8 nodes, 512 threads)
  conv5_gemm<<<N_NODES/8,512,0,stream>>>(h2, W5_rel, W5_root, b5, xr_b, hB);
  k_aggb<<<N_NODES/4,256,0,stream>>>(cnt, slot, xr_b, hB, hB);

  // pool + head
  k_pool<<<(N_NODES/256)+1,256,0,stream>>>(hB, batch, g);
  k_head<<<1,256,0,stream>>>(g, W_fc1, b_fc1, W_fc2, b_fc2, out);
}

// Round 15
// 291.649 us; speedup vs baseline: 1.2596x; 1.2596x over previous
//
#include <hip/hip_runtime.h>
#include <math.h>

#define N_NODES 25000
#define N_EDGES 400000
#define FEAT 128
#define HID 64
#define HEADS 4
#define HH 256   // HEADS*HID
#define NUM_GRAPHS 64
#define BUCKET 96   // max in-degree slots (mean 16, sigma 4 -> P(>96)~1e-80)

typedef unsigned short ushort_t;
typedef unsigned int uint_t;
typedef __attribute__((ext_vector_type(8))) short short8;   // 8 bf16 (4 VGPRs)
typedef __attribute__((ext_vector_type(4))) float f32x4;

__device__ __forceinline__ float lrelu(float x){ return x > 0.f ? x : 0.2f*x; }

// fp32 -> bf16 with round-to-nearest-even
__device__ __forceinline__ ushort_t f2bf(float f){
  uint_t u = __float_as_uint(f);
  return (ushort_t)((u + 0x7fffu + ((u >> 16) & 1u)) >> 16);
}
#define BF_LO(u) __uint_as_float((u) << 16)
#define BF_HI(u) __uint_as_float((u) & 0xffff0000u)

// ============ conv1: dual GEMM (rel+root), K=128 split 2x64, M=64 ============
__global__ __launch_bounds__(256) void conv1_gemm(
    const float* __restrict__ X, const float* __restrict__ Wrel,
    const float* __restrict__ Wroot, const float* __restrict__ bias,
    ushort_t* __restrict__ out_rel_b, float* __restrict__ out_root)
{
  const int w    = __builtin_amdgcn_readfirstlane(threadIdx.x >> 6);
  const int lane = threadIdx.x & 63;
  const int m = w >> 1, q = w & 1;
  const float* Wm = (m ? Wroot : Wrel) + (size_t)q*64*HID;
  float wreg[64];
  #pragma unroll
  for (int k = 0; k < 64; k++) wreg[k] = Wm[k*HID + lane];
  __shared__ float part[2][2][8][64];          // 8 KB
  const int base = blockIdx.x*8;               // exact grid: 3125 blocks
  const float* __restrict__ xr = X + (size_t)base*FEAT + q*64;
  float acc[8] = {0,0,0,0,0,0,0,0};
  #pragma unroll
  for (int k = 0; k < 64; k++){
    const float wv = wreg[k];
    #pragma unroll
    for (int i = 0; i < 8; i++) acc[i] += xr[(size_t)i*FEAT + k]*wv;
  }
  #pragma unroll
  for (int i = 0; i < 8; i++) part[m][q][i][lane] = acc[i];
  __syncthreads();
  #pragma unroll
  for (int t = threadIdx.x; t < 1024; t += 256){
    int mm = t >> 9, ii = (t >> 6) & 7, cc = t & 63;
    float v = part[mm][0][ii][cc] + part[mm][1][ii][cc];
    if (mm) out_root[(size_t)(base+ii)*HID + cc] = v + bias[cc];
    else    out_rel_b[(size_t)(base+ii)*HID + cc] = f2bf(v);
  }
}

// ============ conv5: dual GEMM, K=256 split 4x64, M=64 =======================
__global__ __launch_bounds__(512) void conv5_gemm(
    const float* __restrict__ X, const float* __restrict__ Wrel,
    const float* __restrict__ Wroot, const float* __restrict__ bias,
    ushort_t* __restrict__ out_rel_b, float* __restrict__ out_root)
{
  const int w    = __builtin_amdgcn_readfirstlane(threadIdx.x >> 6);
  const int lane = threadIdx.x & 63;
  const int m = w >> 2, q = w & 3;
  const float* Wm = (m ? Wroot : Wrel) + (size_t)q*64*HID;
  float wreg[64];
  #pragma unroll
  for (int k = 0; k < 64; k++) wreg[k] = Wm[k*HID + lane];
  __shared__ float part[2][4][8][64];          // 16 KB
  const int base = blockIdx.x*8;               // exact grid: 3125 blocks
  const float* __restrict__ xr = X + (size_t)base*HH + q*64;
  float acc[8] = {0,0,0,0,0,0,0,0};
  #pragma unroll
  for (int k = 0; k < 64; k++){
    const float wv = wreg[k];
    #pragma unroll
    for (int i = 0; i < 8; i++) acc[i] += xr[(size_t)i*HH + k]*wv;
  }
  #pragma unroll
  for (int i = 0; i < 8; i++) part[m][q][i][lane] = acc[i];
  __syncthreads();
  #pragma unroll
  for (int t = threadIdx.x; t < 1024; t += 512){
    int mm = t >> 9, ii = (t >> 6) & 7, cc = t & 63;
    float v = part[mm][0][ii][cc] + part[mm][1][ii][cc]
            + part[mm][2][ii][cc] + part[mm][3][ii][cc];
    if (mm) out_root[(size_t)(base+ii)*HID + cc] = v + bias[cc];
    else    out_rel_b[(size_t)(base+ii)*HID + cc] = f2bf(v);
  }
}

// ====== prep: pack Wg (64x256 fp32) into B-frag-ordered bf16 =================
// frag (nt,kt): elem(lane,j) = Wg[kt*32 + (lane>>4)*8 + j][nt*16 + (lane&15)]
__global__ __launch_bounds__(256) void k3_prep(
    const float* __restrict__ Wg, ushort_t* __restrict__ wgb)
{
  const int t = threadIdx.x;
  for (int i = 0; i < 64; i++){
    int e = t*64 + i;
    int j = e & 7, lane = (e >> 3) & 63, kt = (e >> 9) & 1, nt = e >> 10;
    int k = kt*32 + (lane >> 4)*8 + j;
    int n = nt*16 + (lane & 15);
    wgb[e] = f2bf(Wg[k*HH + n]);
  }
}

// ====== GAT transform via MFMA: xl = h1b @ Wg, + head dots from D frags ======
// 391 blocks x 4 waves; wave = 16 nodes (M-tile). 16 n-tiles x 2 K-MFMAs.
// A: A[m=lane&15][k=quad*8+j]; B from wgb; D: col=lane&15, row=quad*4+reg.
__global__ __launch_bounds__(256) void k3_mfma(
    const ushort_t* __restrict__ h1b, const ushort_t* __restrict__ wgb,
    const float* __restrict__ att_src, const float* __restrict__ att_dst,
    ushort_t* __restrict__ xlb, float* __restrict__ a_s, float* __restrict__ a_d)
{
  const int wid  = __builtin_amdgcn_readfirstlane(threadIdx.x >> 6);
  const int lane = threadIdx.x & 63;
  const int quad = lane >> 4, col = lane & 15;
  const int nb = blockIdx.x*64 + wid*16;
  const ushort_t* arow = h1b + (size_t)(nb + col)*HID + quad*8;
  short8 a0 = *(const short8*)(arow);
  short8 a1 = *(const short8*)(arow + 32);
  float as_acc[4] = {0,0,0,0}, ad_acc[4] = {0,0,0,0};
  #pragma unroll
  for (int nt = 0; nt < 16; nt++){
    short8 b0 = *(const short8*)(wgb + ((size_t)(nt*2+0)*64 + lane)*8);
    short8 b1 = *(const short8*)(wgb + ((size_t)(nt*2+1)*64 + lane)*8);
    f32x4 d = {0.f, 0.f, 0.f, 0.f};
    d = __builtin_amdgcn_mfma_f32_16x16x32_bf16(a0, b0, d, 0, 0, 0);
    d = __builtin_amdgcn_mfma_f32_16x16x32_bf16(a1, b1, d, 0, 0, 0);
    const int h = nt >> 2;
    const float asv = att_src[h*HID + (nt & 3)*16 + col];
    const float adv = att_dst[h*HID + (nt & 3)*16 + col];
    #pragma unroll
    for (int r = 0; r < 4; r++){
      const int node = nb + quad*4 + r;
      if (node < N_NODES)
        xlb[(size_t)node*HH + nt*16 + col] = f2bf(d[r]);
      as_acc[r] += d[r]*asv;
      ad_acc[r] += d[r]*adv;
    }
    if ((nt & 3) == 3){                        // finish head h
      #pragma unroll
      for (int r = 0; r < 4; r++){
        float s1 = as_acc[r], s2 = ad_acc[r];
        #pragma unroll
        for (int off = 1; off < 16; off <<= 1){
          s1 += __shfl_xor(s1, off, 64);
          s2 += __shfl_xor(s2, off, 64);
        }
        const int node = nb + quad*4 + r;
        if (col == 0 && node < N_NODES){
          a_s[node*HEADS + h] = s1;
          a_d[node*HEADS + h] = s2;
        }
        as_acc[r] = 0.f; ad_acc[r] = 0.f;
      }
    }
  }
}

// -------- bucketed CSR build: no histogram, no scan --------------------------
__global__ __launch_bounds__(256) void k_fill(const int* __restrict__ src,
                                              const int* __restrict__ dst,
                                              int* __restrict__ cnt,
                                              int* __restrict__ slot)
{
  int e = blockIdx.x*256 + threadIdx.x;
  if (e >= N_EDGES) return;
  int d = dst[e];
  int pos = atomicAdd(&cnt[d], 1);
  if (pos < BUCKET) slot[(size_t)d*BUCKET + pos] = src[e];
}

// -------- gather agg: wave=node, lane=column; templated output dtype ---------
template<bool BF16OUT>
__global__ __launch_bounds__(256) void k_aggb(
    const int* __restrict__ cnt, const int* __restrict__ slot,
    const ushort_t* __restrict__ featb, const float* __restrict__ root,
    float* __restrict__ outf, ushort_t* __restrict__ outb)
{
  const int node = blockIdx.x*4 + (threadIdx.x >> 6);   // grid exact: 6250*4
  const int lane = threadIdx.x & 63;
  const int* __restrict__ sl = slot + (size_t)node*BUCKET;
  const int deg = min(cnt[node], BUCKET);
  float acc = root[(size_t)node*HID + lane];
  int e = 0;
  for (; e + 4 <= deg; e += 4){
    int sA = sl[e],   sB = sl[e+1];
    int sC = sl[e+2], sD = sl[e+3];
    float xA = BF_LO((uint_t)featb[(size_t)sA*HID + lane]);
    float xB = BF_LO((uint_t)featb[(size_t)sB*HID + lane]);
    float xC = BF_LO((uint_t)featb[(size_t)sC*HID + lane]);
    float xD = BF_LO((uint_t)featb[(size_t)sD*HID + lane]);
    acc += xA; acc += xB; acc += xC; acc += xD;
  }
  for (; e < deg; e++){
    int s = sl[e];
    acc += BF_LO((uint_t)featb[(size_t)s*HID + lane]);
  }
  const float v = fmaxf(acc, 0.f);
  if (BF16OUT) outb[(size_t)node*HID + lane] = f2bf(v);
  else         outf[(size_t)node*HID + lane] = v;
}

// ---- GAT softmax+aggregate v4: wave = node (ALL 4 heads) --------------------
__global__ __launch_bounds__(256) void k_gat_node(
    const int* __restrict__ cnt, const int* __restrict__ slot,
    const uint2* __restrict__ xl2,      // bf16 node-major: idx = node*64 + lane
    const float* __restrict__ a_s, const float* __restrict__ a_d,
    const float* __restrict__ bg, float* __restrict__ h2)
{
  const int node = blockIdx.x*4 + (threadIdx.x >> 6);   // grid exact: 6250*4
  const int lane = threadIdx.x & 63;
  const int h  = lane >> 4;
  const int el = lane & 15;
  const int* __restrict__ sl = slot + (size_t)node*BUCKET;
  const int deg = min(cnt[node], BUCKET);
  const float adh = a_d[node*HEADS + h];
  float acc0=0, acc1=0, acc2=0, acc3=0;
  float dsum = 0.f;
  for (int base = 0; base < deg; base += 16){
    float pme = 0.f; int sme = node;
    const int e = base + el;
    if (e < deg){
      sme = sl[e];
      pme = __expf(lrelu(a_s[sme*HEADS + h] + adh));
    }
    dsum += pme;
    const int nsub = min(16, deg - base);
    int e4 = 0;
    for (; e4 + 2 <= nsub; e4 += 2){
      const int b0 = (lane & 48) + e4;
      const float pA = __shfl(pme, b0, 64);
      const int   sA = __shfl(sme, b0, 64);
      const float pB = __shfl(pme, b0 + 1, 64);
      const int   sB = __shfl(sme, b0 + 1, 64);
      uint2 rA = xl2[(size_t)sA*64 + lane];
      uint2 rB = xl2[(size_t)sB*64 + lane];
      acc0 += pA*BF_LO(rA.x); acc1 += pA*BF_HI(rA.x);
      acc2 += pA*BF_LO(rA.y); acc3 += pA*BF_HI(rA.y);
      acc0 += pB*BF_LO(rB.x); acc1 += pB*BF_HI(rB.x);
      acc2 += pB*BF_LO(rB.y); acc3 += pB*BF_HI(rB.y);
    }
    if (e4 < nsub){
      const int b0 = (lane & 48) + e4;
      const float pA = __shfl(pme, b0, 64);
      const int   sA = __shfl(sme, b0, 64);
      uint2 rA = xl2[(size_t)sA*64 + lane];
      acc0 += pA*BF_LO(rA.x); acc1 += pA*BF_HI(rA.x);
      acc2 += pA*BF_LO(rA.y); acc3 += pA*BF_HI(rA.y);
    }
  }
  #pragma unroll
  for (int off = 1; off < 16; off <<= 1) dsum += __shfl_xor(dsum, off, 64);
  const float pself = __expf(lrelu(a_s[node*HEADS + h] + adh));
  const float inv = 1.f / (dsum + pself);
  uint2 r = xl2[(size_t)node*64 + lane];
  acc0 += pself*BF_LO(r.x); acc1 += pself*BF_HI(r.x);
  acc2 += pself*BF_LO(r.y); acc3 += pself*BF_HI(r.y);
  const int col0 = lane*4;          // = h*64 + el*4
  float4 o;
  o.x = fmaxf(acc0*inv + bg[col0+0], 0.f);
  o.y = fmaxf(acc1*inv + bg[col0+1], 0.f);
  o.z = fmaxf(acc2*inv + bg[col0+2], 0.f);
  o.w = fmaxf(acc3*inv + bg[col0+3], 0.f);
  ((float4*)(h2 + (size_t)node*HH))[lane] = o;
}

// ---------------- pool: run-length segment reduce over sorted batch ----------
__global__ __launch_bounds__(256) void k_pool(
    const float* __restrict__ h3, const int* __restrict__ batch,
    float* __restrict__ g)
{
  const int w = blockIdx.x*4 + (threadIdx.x >> 6);
  const int j = threadIdx.x & 63;
  int n0 = w*64;
  if (n0 >= N_NODES) return;
  int n1 = min(n0+64, N_NODES);
  float acc = 0.f;
  int cur = batch[n0];
  for (int n = n0; n < n1; n++){
    int b = batch[n];
    if (b != cur){ atomicAdd(&g[cur*HID + j], acc); acc = 0.f; cur = b; }
    acc += h3[n*HID + j];
  }
  atomicAdd(&g[cur*HID + j], acc);
}

__global__ __launch_bounds__(256) void k_head(
    const float* __restrict__ g, const float* __restrict__ W1,
    const float* __restrict__ b1, const float* __restrict__ W2,
    const float* __restrict__ b2, float* __restrict__ out)
{
  __shared__ float gs[NUM_GRAPHS*HID];
  __shared__ float hh[NUM_GRAPHS*HID];
  for (int i = threadIdx.x; i < NUM_GRAPHS*HID; i += 256) gs[i] = g[i];
  __syncthreads();
  for (int t = threadIdx.x; t < NUM_GRAPHS*HID; t += 256){
    int b = t >> 6, j = t & 63;
    float acc = b1[j];
    for (int k = 0; k < HID; k++) acc += gs[b*HID+k]*W1[k*HID+j];
    hh[t] = fmaxf(acc, 0.f);
  }
  __syncthreads();
  for (int t = threadIdx.x; t < NUM_GRAPHS*2; t += 256){
    int b = t >> 1, c = t & 1;
    float acc = b2[c];
    for (int k = 0; k < HID; k++) acc += hh[b*HID+k]*W2[k*2+c];
    out[t] = 1.f / (1.f + __expf(-acc));
  }
}

extern "C" void kernel_launch(void* const* d_in, const int* in_sizes, int n_in,
                              void* d_out, int out_size, void* d_ws, size_t ws_size,
                              hipStream_t stream)
{
  const float* x       = (const float*)d_in[0];
  const int*   ei      = (const int*)d_in[1];
  const int*   batch   = (const int*)d_in[2];
  const float* W1_rel  = (const float*)d_in[3];
  const float* b1      = (const float*)d_in[4];
  const float* W1_root = (const float*)d_in[5];
  const float* Wg      = (const float*)d_in[6];
  const float* att_src = (const float*)d_in[7];
  const float* att_dst = (const float*)d_in[8];
  const float* bg      = (const float*)d_in[9];
  const float* W5_rel  = (const float*)d_in[10];
  const float* b5      = (const float*)d_in[11];
  const float* W5_root = (const float*)d_in[12];
  const float* W_fc1   = (const float*)d_in[13];
  const float* b_fc1   = (const float*)d_in[14];
  const float* W_fc2   = (const float*)d_in[15];
  const float* b_fc2   = (const float*)d_in[16];
  const int* src = ei;
  const int* dst = ei + N_EDGES;

  // ---- workspace layout, FLOAT (4-byte) units, all 16B-aligned -------------
  float* ws    = (float*)d_ws;
  ushort_t* xr_b = (ushort_t*)ws;            // bf16 N*64       [0, 800000)
  float* hB    = ws +   800000;              // f32  N*64       [800000, 2400000)
  ushort_t* h1b = (ushort_t*)(ws + 2400000); // bf16 (N+24)*64  [2400000, 3201024)
  ushort_t* xlb = (ushort_t*)(ws + 3201024); // bf16 N*256      [3201024, 6401024)
  float* a_s   = ws +  6401024;              // f32 N*4
  float* a_d   = ws +  6501024;              // f32 N*4
  float* h2    = ws +  6601024;              // f32 N*256       [6601024, 13001024)
  float* g     = ws + 13001024;              // 4096
  int*   cnt   = (int*)(ws + 13005120);      // 25000 (adjacent to g -> 1 memset)
  ushort_t* wgb = (ushort_t*)(ws + 13040000);// 16384 bf16 (B-frag packed)
  int*   slot  = (int*)(ws + 13050000);      // 25000*96 = 2.4M ints
  float* out   = (float*)d_out;

  // bucketed CSR build (+ zero g and cnt in the same memset); pack Wg frags
  hipMemsetAsync(g, 0, (4096 + N_NODES)*sizeof(float), stream);
  k_fill<<<(N_EDGES+255)/256,256,0,stream>>>(src, dst, cnt, slot);
  k3_prep<<<1,256,0,stream>>>(Wg, wgb);

  // conv1  (3125 blocks x 8 nodes); agg emits h1 in bf16 (feeds MFMA)
  conv1_gemm<<<N_NODES/8,256,0,stream>>>(x, W1_rel, W1_root, b1, xr_b, hB);
  k_aggb<true><<<N_NODES/4,256,0,stream>>>(cnt, slot, xr_b, hB, nullptr, h1b);

  // GAT: MFMA transform (391 blocks x 4 waves x 16 nodes) + fused softmax-agg
  k3_mfma<<<(N_NODES+63)/64,256,0,stream>>>(h1b, wgb, att_src, att_dst,
                                            xlb, a_s, a_d);
  k_gat_node<<<N_NODES/4,256,0,stream>>>(cnt, slot,
      (const uint2*)xlb, a_s, a_d, bg, h2);

  // conv5  (3125 blocks x 8 nodes, 512 threads)
  conv5_gemm<<<N_NODES/8,512,0,stream>>>(h2, W5_rel, W5_root, b5, xr_b, hB);
  k_aggb<false><<<N_NODES/4,256,0,stream>>>(cnt, slot, xr_b, hB, hB, nullptr);

  // pool + head
  k_pool<<<(N_NODES/256)+1,256,0,stream>>>(hB, batch, g);
  k_head<<<1,256,0,stream>>>(g, W_fc1, b_fc1, W_fc2, b_fc2, out);
}

// Round 16
// 255.059 us; speedup vs baseline: 1.4403x; 1.1435x over previous
//
#include <hip/hip_runtime.h>
#include <math.h>

#define N_NODES 25000
#define N_EDGES 400000
#define FEAT 128
#define HID 64
#define HEADS 4
#define HH 256   // HEADS*HID
#define NUM_GRAPHS 64
#define BUCKET 96   // max in-degree slots (mean 16, sigma 4 -> P(>96)~1e-80)

typedef unsigned short ushort_t;
typedef unsigned int uint_t;
typedef __attribute__((ext_vector_type(8))) short short8;   // 8 bf16 (4 VGPRs)
typedef __attribute__((ext_vector_type(4))) float f32x4;

__device__ __forceinline__ float lrelu(float x){ return x > 0.f ? x : 0.2f*x; }

// fp32 -> bf16 with round-to-nearest-even
__device__ __forceinline__ ushort_t f2bf(float f){
  uint_t u = __float_as_uint(f);
  return (ushort_t)((u + 0x7fffu + ((u >> 16) & 1u)) >> 16);
}
#define BF_LO(u) __uint_as_float((u) << 16)
#define BF_HI(u) __uint_as_float((u) & 0xffff0000u)

// ====== pack all weight matrices into B-frag-ordered bf16 ====================
// B frag (nt,kc) elem(lane,j) = W[kc*32 + (lane>>4)*8 + j][nt*16 + (lane&15)]
// wc1b: [Wrel|Wroot] 128x128 (nt<8,kc<4); wc5b: 256x128 (nt<8,kc<8);
// wgb: Wg 64x256 (nt<16,kt<2).
__global__ __launch_bounds__(256) void k_pack(
    const float* __restrict__ W1_rel, const float* __restrict__ W1_root,
    const float* __restrict__ W5_rel, const float* __restrict__ W5_root,
    const float* __restrict__ Wg,
    ushort_t* __restrict__ wc1b, ushort_t* __restrict__ wc5b,
    ushort_t* __restrict__ wgb)
{
  const int e = blockIdx.x*256 + threadIdx.x;   // grid 64 -> e in [0,16384)
  { // conv1
    int j=e&7, lane=(e>>3)&63, kc=(e>>9)&3, nt=e>>11;
    int k = kc*32 + (lane>>4)*8 + j, n = nt*16 + (lane&15);
    float v = (n < 64) ? W1_rel[k*64 + n] : W1_root[k*64 + n - 64];
    wc1b[e] = f2bf(v);
  }
  { // k3 (R15-verified mapping)
    int j=e&7, lane=(e>>3)&63, kt=(e>>9)&1, nt=e>>10;
    int k = kt*32 + (lane>>4)*8 + j, n = nt*16 + (lane&15);
    wgb[e] = f2bf(Wg[k*HH + n]);
  }
  #pragma unroll
  for (int e5 = e; e5 < 32768; e5 += 16384){ // conv5
    int j=e5&7, lane=(e5>>3)&63, kc=(e5>>9)&7, nt=e5>>12;
    int k = kc*32 + (lane>>4)*8 + j, n = nt*16 + (lane&15);
    float v = (n < 64) ? W5_rel[k*64 + n] : W5_root[k*64 + n - 64];
    wc5b[e5] = f2bf(v);
  }
}

// ====== conv1 via MFMA: [rel|root] = x @ [Wrel|Wroot], K=128, M=128 ==========
// wave = 16 nodes; A built from f32 x with in-register bf16 cvt.
__global__ __launch_bounds__(256) void conv1_mfma(
    const float* __restrict__ X, const ushort_t* __restrict__ wc1b,
    const float* __restrict__ bias,
    ushort_t* __restrict__ out_rel_b, float* __restrict__ out_root)
{
  const int wid  = __builtin_amdgcn_readfirstlane(threadIdx.x >> 6);
  const int lane = threadIdx.x & 63;
  const int quad = lane >> 4, col = lane & 15;
  const int nb = blockIdx.x*64 + wid*16;
  if (nb >= N_NODES) return;
  const int row = min(nb + col, N_NODES-1);
  const float* __restrict__ xr = X + (size_t)row*FEAT + quad*8;
  short8 a[4];
  #pragma unroll
  for (int kc = 0; kc < 4; kc++){
    #pragma unroll
    for (int j = 0; j < 8; j++)
      ((ushort_t*)&a[kc])[j] = f2bf(xr[kc*32 + j]);
  }
  #pragma unroll
  for (int nt = 0; nt < 8; nt++){
    f32x4 d = {0.f,0.f,0.f,0.f};
    #pragma unroll
    for (int kc = 0; kc < 4; kc++){
      short8 b = *(const short8*)(wc1b + ((size_t)(nt*4+kc)*64 + lane)*8);
      d = __builtin_amdgcn_mfma_f32_16x16x32_bf16(a[kc], b, d, 0, 0, 0);
    }
    if (nt < 4){
      #pragma unroll
      for (int r = 0; r < 4; r++){
        const int node = nb + quad*4 + r;
        if (node < N_NODES)
          out_rel_b[(size_t)node*HID + nt*16 + col] = f2bf(d[r]);
      }
    } else {
      const float bv = bias[(nt-4)*16 + col];
      #pragma unroll
      for (int r = 0; r < 4; r++){
        const int node = nb + quad*4 + r;
        if (node < N_NODES)
          out_root[(size_t)node*HID + (nt-4)*16 + col] = d[r] + bv;
      }
    }
  }
}

// ====== conv5 via MFMA: [rel|root] = h2b @ [Wrel|Wroot], K=256, M=128 ========
__global__ __launch_bounds__(256) void conv5_mfma(
    const ushort_t* __restrict__ h2b, const ushort_t* __restrict__ wc5b,
    const float* __restrict__ bias,
    ushort_t* __restrict__ out_rel_b, float* __restrict__ out_root)
{
  const int wid  = __builtin_amdgcn_readfirstlane(threadIdx.x >> 6);
  const int lane = threadIdx.x & 63;
  const int quad = lane >> 4, col = lane & 15;
  const int nb = blockIdx.x*64 + wid*16;
  if (nb >= N_NODES) return;
  const ushort_t* __restrict__ arow = h2b + (size_t)(nb + col)*HH + quad*8;
  short8 a[8];
  #pragma unroll
  for (int kc = 0; kc < 8; kc++)
    a[kc] = *(const short8*)(arow + kc*32);
  #pragma unroll
  for (int nt = 0; nt < 8; nt++){
    f32x4 d = {0.f,0.f,0.f,0.f};
    #pragma unroll
    for (int kc = 0; kc < 8; kc++){
      short8 b = *(const short8*)(wc5b + ((size_t)(nt*8+kc)*64 + lane)*8);
      d = __builtin_amdgcn_mfma_f32_16x16x32_bf16(a[kc], b, d, 0, 0, 0);
    }
    if (nt < 4){
      #pragma unroll
      for (int r = 0; r < 4; r++){
        const int node = nb + quad*4 + r;
        if (node < N_NODES)
          out_rel_b[(size_t)node*HID + nt*16 + col] = f2bf(d[r]);
      }
    } else {
      const float bv = bias[(nt-4)*16 + col];
      #pragma unroll
      for (int r = 0; r < 4; r++){
        const int node = nb + quad*4 + r;
        if (node < N_NODES)
          out_root[(size_t)node*HID + (nt-4)*16 + col] = d[r] + bv;
      }
    }
  }
}

// ====== GAT transform via MFMA: xl = h1b @ Wg, + head dots from D frags ======
__global__ __launch_bounds__(256) void k3_mfma(
    const ushort_t* __restrict__ h1b, const ushort_t* __restrict__ wgb,
    const float* __restrict__ att_src, const float* __restrict__ att_dst,
    ushort_t* __restrict__ xlb, float* __restrict__ a_s, float* __restrict__ a_d)
{
  const int wid  = __builtin_amdgcn_readfirstlane(threadIdx.x >> 6);
  const int lane = threadIdx.x & 63;
  const int quad = lane >> 4, col = lane & 15;
  const int nb = blockIdx.x*64 + wid*16;
  const ushort_t* arow = h1b + (size_t)(nb + col)*HID + quad*8;
  short8 a0 = *(const short8*)(arow);
  short8 a1 = *(const short8*)(arow + 32);
  float as_acc[4] = {0,0,0,0}, ad_acc[4] = {0,0,0,0};
  #pragma unroll
  for (int nt = 0; nt < 16; nt++){
    short8 b0 = *(const short8*)(wgb + ((size_t)(nt*2+0)*64 + lane)*8);
    short8 b1 = *(const short8*)(wgb + ((size_t)(nt*2+1)*64 + lane)*8);
    f32x4 d = {0.f, 0.f, 0.f, 0.f};
    d = __builtin_amdgcn_mfma_f32_16x16x32_bf16(a0, b0, d, 0, 0, 0);
    d = __builtin_amdgcn_mfma_f32_16x16x32_bf16(a1, b1, d, 0, 0, 0);
    const int h = nt >> 2;
    const float asv = att_src[h*HID + (nt & 3)*16 + col];
    const float adv = att_dst[h*HID + (nt & 3)*16 + col];
    #pragma unroll
    for (int r = 0; r < 4; r++){
      const int node = nb + quad*4 + r;
      if (node < N_NODES)
        xlb[(size_t)node*HH + nt*16 + col] = f2bf(d[r]);
      as_acc[r] += d[r]*asv;
      ad_acc[r] += d[r]*adv;
    }
    if ((nt & 3) == 3){                        // finish head h
      #pragma unroll
      for (int r = 0; r < 4; r++){
        float s1 = as_acc[r], s2 = ad_acc[r];
        #pragma unroll
        for (int off = 1; off < 16; off <<= 1){
          s1 += __shfl_xor(s1, off, 64);
          s2 += __shfl_xor(s2, off, 64);
        }
        const int node = nb + quad*4 + r;
        if (col == 0 && node < N_NODES){
          a_s[node*HEADS + h] = s1;
          a_d[node*HEADS + h] = s2;
        }
        as_acc[r] = 0.f; ad_acc[r] = 0.f;
      }
    }
  }
}

// -------- bucketed CSR build: no histogram, no scan --------------------------
__global__ __launch_bounds__(256) void k_fill(const int* __restrict__ src,
                                              const int* __restrict__ dst,
                                              int* __restrict__ cnt,
                                              int* __restrict__ slot)
{
  int e = blockIdx.x*256 + threadIdx.x;
  if (e >= N_EDGES) return;
  int d = dst[e];
  int pos = atomicAdd(&cnt[d], 1);
  if (pos < BUCKET) slot[(size_t)d*BUCKET + pos] = src[e];
}

// -------- gather agg: wave=node, lane=column; templated output dtype ---------
template<bool BF16OUT>
__global__ __launch_bounds__(256) void k_aggb(
    const int* __restrict__ cnt, const int* __restrict__ slot,
    const ushort_t* __restrict__ featb, const float* __restrict__ root,
    float* __restrict__ outf, ushort_t* __restrict__ outb)
{
  const int node = blockIdx.x*4 + (threadIdx.x >> 6);   // grid exact: 6250*4
  const int lane = threadIdx.x & 63;
  const int* __restrict__ sl = slot + (size_t)node*BUCKET;
  const int deg = min(cnt[node], BUCKET);
  float acc = root[(size_t)node*HID + lane];
  int e = 0;
  for (; e + 4 <= deg; e += 4){
    int sA = sl[e],   sB = sl[e+1];
    int sC = sl[e+2], sD = sl[e+3];
    float xA = BF_LO((uint_t)featb[(size_t)sA*HID + lane]);
    float xB = BF_LO((uint_t)featb[(size_t)sB*HID + lane]);
    float xC = BF_LO((uint_t)featb[(size_t)sC*HID + lane]);
    float xD = BF_LO((uint_t)featb[(size_t)sD*HID + lane]);
    acc += xA; acc += xB; acc += xC; acc += xD;
  }
  for (; e < deg; e++){
    int s = sl[e];
    acc += BF_LO((uint_t)featb[(size_t)s*HID + lane]);
  }
  const float v = fmaxf(acc, 0.f);
  if (BF16OUT) outb[(size_t)node*HID + lane] = f2bf(v);
  else         outf[(size_t)node*HID + lane] = v;
}

// ---- GAT softmax+aggregate v4: wave = node (ALL 4 heads); bf16 output -------
__global__ __launch_bounds__(256) void k_gat_node(
    const int* __restrict__ cnt, const int* __restrict__ slot,
    const uint2* __restrict__ xl2,      // bf16 node-major: idx = node*64 + lane
    const float* __restrict__ a_s, const float* __restrict__ a_d,
    const float* __restrict__ bg, ushort_t* __restrict__ h2b)
{
  const int node = blockIdx.x*4 + (threadIdx.x >> 6);   // grid exact: 6250*4
  const int lane = threadIdx.x & 63;
  const int h  = lane >> 4;
  const int el = lane & 15;
  const int* __restrict__ sl = slot + (size_t)node*BUCKET;
  const int deg = min(cnt[node], BUCKET);
  const float adh = a_d[node*HEADS + h];
  float acc0=0, acc1=0, acc2=0, acc3=0;
  float dsum = 0.f;
  for (int base = 0; base < deg; base += 16){
    float pme = 0.f; int sme = node;
    const int e = base + el;
    if (e < deg){
      sme = sl[e];
      pme = __expf(lrelu(a_s[sme*HEADS + h] + adh));
    }
    dsum += pme;
    const int nsub = min(16, deg - base);
    int e4 = 0;
    for (; e4 + 2 <= nsub; e4 += 2){
      const int b0 = (lane & 48) + e4;
      const float pA = __shfl(pme, b0, 64);
      const int   sA = __shfl(sme, b0, 64);
      const float pB = __shfl(pme, b0 + 1, 64);
      const int   sB = __shfl(sme, b0 + 1, 64);
      uint2 rA = xl2[(size_t)sA*64 + lane];
      uint2 rB = xl2[(size_t)sB*64 + lane];
      acc0 += pA*BF_LO(rA.x); acc1 += pA*BF_HI(rA.x);
      acc2 += pA*BF_LO(rA.y); acc3 += pA*BF_HI(rA.y);
      acc0 += pB*BF_LO(rB.x); acc1 += pB*BF_HI(rB.x);
      acc2 += pB*BF_LO(rB.y); acc3 += pB*BF_HI(rB.y);
    }
    if (e4 < nsub){
      const int b0 = (lane & 48) + e4;
      const float pA = __shfl(pme, b0, 64);
      const int   sA = __shfl(sme, b0, 64);
      uint2 rA = xl2[(size_t)sA*64 + lane];
      acc0 += pA*BF_LO(rA.x); acc1 += pA*BF_HI(rA.x);
      acc2 += pA*BF_LO(rA.y); acc3 += pA*BF_HI(rA.y);
    }
  }
  #pragma unroll
  for (int off = 1; off < 16; off <<= 1) dsum += __shfl_xor(dsum, off, 64);
  const float pself = __expf(lrelu(a_s[node*HEADS + h] + adh));
  const float inv = 1.f / (dsum + pself);
  uint2 r = xl2[(size_t)node*64 + lane];
  acc0 += pself*BF_LO(r.x); acc1 += pself*BF_HI(r.x);
  acc2 += pself*BF_LO(r.y); acc3 += pself*BF_HI(r.y);
  const int col0 = lane*4;          // = h*64 + el*4
  const float ox = fmaxf(acc0*inv + bg[col0+0], 0.f);
  const float oy = fmaxf(acc1*inv + bg[col0+1], 0.f);
  const float oz = fmaxf(acc2*inv + bg[col0+2], 0.f);
  const float ow = fmaxf(acc3*inv + bg[col0+3], 0.f);
  uint2 o;
  o.x = (uint_t)f2bf(ox) | ((uint_t)f2bf(oy) << 16);
  o.y = (uint_t)f2bf(oz) | ((uint_t)f2bf(ow) << 16);
  ((uint2*)(h2b + (size_t)node*HH))[lane] = o;
}

// ---------------- pool: run-length segment reduce over sorted batch ----------
__global__ __launch_bounds__(256) void k_pool(
    const float* __restrict__ h3, const int* __restrict__ batch,
    float* __restrict__ g)
{
  const int w = blockIdx.x*4 + (threadIdx.x >> 6);
  const int j = threadIdx.x & 63;
  int n0 = w*64;
  if (n0 >= N_NODES) return;
  int n1 = min(n0+64, N_NODES);
  float acc = 0.f;
  int cur = batch[n0];
  for (int n = n0; n < n1; n++){
    int b = batch[n];
    if (b != cur){ atomicAdd(&g[cur*HID + j], acc); acc = 0.f; cur = b; }
    acc += h3[n*HID + j];
  }
  atomicAdd(&g[cur*HID + j], acc);
}

__global__ __launch_bounds__(256) void k_head(
    const float* __restrict__ g, const float* __restrict__ W1,
    const float* __restrict__ b1, const float* __restrict__ W2,
    const float* __restrict__ b2, float* __restrict__ out)
{
  __shared__ float gs[NUM_GRAPHS*HID];
  __shared__ float hh[NUM_GRAPHS*HID];
  for (int i = threadIdx.x; i < NUM_GRAPHS*HID; i += 256) gs[i] = g[i];
  __syncthreads();
  for (int t = threadIdx.x; t < NUM_GRAPHS*HID; t += 256){
    int b = t >> 6, j = t & 63;
    float acc = b1[j];
    for (int k = 0; k < HID; k++) acc += gs[b*HID+k]*W1[k*HID+j];
    hh[t] = fmaxf(acc, 0.f);
  }
  __syncthreads();
  for (int t = threadIdx.x; t < NUM_GRAPHS*2; t += 256){
    int b = t >> 1, c = t & 1;
    float acc = b2[c];
    for (int k = 0; k < HID; k++) acc += hh[b*HID+k]*W2[k*2+c];
    out[t] = 1.f / (1.f + __expf(-acc));
  }
}

extern "C" void kernel_launch(void* const* d_in, const int* in_sizes, int n_in,
                              void* d_out, int out_size, void* d_ws, size_t ws_size,
                              hipStream_t stream)
{
  const float* x       = (const float*)d_in[0];
  const int*   ei      = (const int*)d_in[1];
  const int*   batch   = (const int*)d_in[2];
  const float* W1_rel  = (const float*)d_in[3];
  const float* b1      = (const float*)d_in[4];
  const float* W1_root = (const float*)d_in[5];
  const float* Wg      = (const float*)d_in[6];
  const float* att_src = (const float*)d_in[7];
  const float* att_dst = (const float*)d_in[8];
  const float* bg      = (const float*)d_in[9];
  const float* W5_rel  = (const float*)d_in[10];
  const float* b5      = (const float*)d_in[11];
  const float* W5_root = (const float*)d_in[12];
  const float* W_fc1   = (const float*)d_in[13];
  const float* b_fc1   = (const float*)d_in[14];
  const float* W_fc2   = (const float*)d_in[15];
  const float* b_fc2   = (const float*)d_in[16];
  const int* src = ei;
  const int* dst = ei + N_EDGES;

  // ---- workspace layout, FLOAT (4-byte) units, all 16B-aligned -------------
  float* ws    = (float*)d_ws;
  ushort_t* xr_b = (ushort_t*)ws;            // bf16 N*64        [0, 800000)
  float* hB    = ws +   800000;              // f32  N*64        [800000, 2400000)
  ushort_t* h1b = (ushort_t*)(ws + 2400000); // bf16 25024*64    [2400000, 3200768)
  ushort_t* xlb = (ushort_t*)(ws + 3200768); // bf16 N*256       [3200768, 6400768)
  float* a_s   = ws +  6400768;              // f32 N*4
  float* a_d   = ws +  6500768;              // f32 N*4
  ushort_t* h2b = (ushort_t*)(ws + 6600768); // bf16 25024*256   [6600768, 9803840)
  float* g     = ws +  9803840;              // 4096
  int*   cnt   = (int*)(ws + 9807936);       // 25000 (adjacent to g -> 1 memset)
  ushort_t* wc1b = (ushort_t*)(ws + 9833600);// 16384 bf16 = 8192 fu
  ushort_t* wc5b = (ushort_t*)(ws + 9841792);// 32768 bf16 = 16384 fu
  ushort_t* wgb  = (ushort_t*)(ws + 9858176);// 16384 bf16 = 8192 fu
  int*   slot  = (int*)(ws + 9870000);       // 25000*96 = 2.4M ints
  float* out   = (float*)d_out;

  // bucketed CSR build (+ zero g and cnt in one memset); pack all weights
  hipMemsetAsync(g, 0, (4096 + N_NODES)*sizeof(float), stream);
  k_fill<<<(N_EDGES+255)/256,256,0,stream>>>(src, dst, cnt, slot);
  k_pack<<<64,256,0,stream>>>(W1_rel, W1_root, W5_rel, W5_root, Wg,
                              wc1b, wc5b, wgb);

  // conv1 (MFMA, 391 blocks x 4 waves x 16 nodes)
  conv1_mfma<<<(N_NODES+63)/64,256,0,stream>>>(x, wc1b, b1, xr_b, hB);
  k_aggb<true><<<N_NODES/4,256,0,stream>>>(cnt, slot, xr_b, hB, nullptr, h1b);

  // GAT: MFMA transform + fused softmax-agg (bf16 out)
  k3_mfma<<<(N_NODES+63)/64,256,0,stream>>>(h1b, wgb, att_src, att_dst,
                                            xlb, a_s, a_d);
  k_gat_node<<<N_NODES/4,256,0,stream>>>(cnt, slot,
      (const uint2*)xlb, a_s, a_d, bg, h2b);

  // conv5 (MFMA)
  conv5_mfma<<<(N_NODES+63)/64,256,0,stream>>>(h2b, wc5b, b5, xr_b, hB);
  k_aggb<false><<<N_NODES/4,256,0,stream>>>(cnt, slot, xr_b, hB, hB, nullptr);

  // pool + head
  k_pool<<<(N_NODES/256)+1,256,0,stream>>>(hB, batch, g);
  k_head<<<1,256,0,stream>>>(g, W_fc1, b_fc1, W_fc2, b_fc2, out);
}